// Round 15
// baseline (123.609 us; speedup 1.0000x reference)
//
#include <hip/hip_runtime.h>
#include <stdint.h>

// S3FD anchor assignment — single-pass pair enumeration, round 15.
// d_in[0]: anchor [N,4] f32, d_in[1]: gt [M,4] f32. d_out: assign [N] int32.
//
// Round 14 post-mortem: k_scatass 50 us (42 MB HBM writes from scattered
// 16B binnedBox stores = 3.5x partial-line amplification) + k_top3 40 us
// existed only to consume the binned array. Key insight: the assign loop's
// gtIds candidate lists already enumerate every inter>0 pair, so per-GT
// top-3 is accumulated IN THE SAME PASS via per-block LDS top-3 tables
// (concurrent atomicMax cascade, provably sorted top-3: each atomicMax
// preserves the {slot,carry} multiset, slots are monotone, dropped values
// are <= all final slots; unique keys -> no tie duplication). Binning
// (hist/scan-prefix/scatter/binned arrays/k_top3) deleted. 3 dispatches:
//   k_prep   - 1 block: per-cell GT lists + seed final3
//   k_main   - 1024 blocks: assign + LDS top-3 insert + global cascade merge
//   k_claims - 1 block: forced-claim scatter-max via LDS hash (proven)
//
// Key encoding (exact jax semantics), per-GT top-3:
//   key = (iou_bits << 32) | ~anchor_idx    (stable top_k: higher iou, then
//                                            lower anchor index wins)
// final3 pre-seeded with (0,~0),(0,~1),(0,~2): reproduces the reference's
// index-ordered zero fill (proven benign rounds 8-14: seed-valued slots can
// only surface where the claim dies on the > 0.1 gate, and the k==0 claim
// in the all-zero case yields anchor 0 == reference ranks[m,0]).

typedef unsigned int u32;
typedef unsigned short u16;
typedef unsigned long long u64;

#define POS_THRESH 0.5f
#define NEG_THRESH 0.3f
#define CLAIM_THRESH 0.1f

constexpr int NCX = 32, NCY = 32, NCELL = NCX * NCY;  // 32x32 cells, 32 px
constexpr float INV_CELL = 0.03125f;                  // 1/32
constexpr float MARGIN = 64.5f;   // max anchor half-extent (<64.001) + slack
constexpr int MPAD = 256;         // padded GT count (M = 200)
constexpr int HSLOTS = 1024;      // claims hash table slots
constexpr int GRID_MAIN = 1024;   // k_main blocks (4/CU, 16 waves/CU)

// IoU expression verbatim from the passing rounds (numpy-exact).
#define IOU_EVAL(a, areaA, g, areaG, inter, iou) {                \
    float ltx = fmaxf(a.x, g.x), lty = fmaxf(a.y, g.y);           \
    float rbx = fminf(a.z, g.z), rby = fminf(a.w, g.w);           \
    float ww = fmaxf(rbx - ltx, 0.0f);                            \
    float hh = fmaxf(rby - lty, 0.0f);                            \
    inter = ww * hh;                                              \
    iou = 0.0f;                                                   \
    if (inter > 0.0f) iou = inter / ((areaA + areaG) - inter);    \
}

__device__ __forceinline__ int cell_of(const float4 a) {
    float cx = 0.5f * (a.x + a.z);
    float cy = 0.5f * (a.y + a.w);
    int ix = (int)(cx * INV_CELL);
    int iy = (int)(cy * INV_CELL);
    ix = ix < 0 ? 0 : (ix > NCX - 1 ? NCX - 1 : ix);
    iy = iy < 0 ? 0 : (iy > NCY - 1 ? NCY - 1 : iy);
    return iy * NCX + ix;
}

__device__ __forceinline__ void gt_range(const float4 g, int& clx, int& chx,
                                         int& cly, int& chy) {
    clx = (int)floorf((g.x - MARGIN) * INV_CELL);
    chx = (int)floorf((g.z + MARGIN) * INV_CELL);
    cly = (int)floorf((g.y - MARGIN) * INV_CELL);
    chy = (int)floorf((g.w + MARGIN) * INV_CELL);
    clx = clx < 0 ? 0 : (clx > NCX - 1 ? NCX - 1 : clx);
    chx = chx < 0 ? 0 : (chx > NCX - 1 ? NCX - 1 : chx);
    cly = cly < 0 ? 0 : (cly > NCY - 1 ? NCY - 1 : cly);
    chy = chy < 0 ? 0 : (chy > NCY - 1 ? NCY - 1 : chy);
}

// Concurrent sorted top-3 insert: atomicMax cascade. Safe under races:
// each atomicMax swaps {slot, carry} as a multiset; slots monotone rise;
// any dropped value was <= all three slots at its ops -> <= final slots.
#define CASCADE3(p0, p1, p2, key) {                               \
    u64 x_ = (key);                                               \
    u64 o_ = atomicMax(&(p0), x_); x_ = o_ < x_ ? o_ : x_;        \
    o_ = atomicMax(&(p1), x_); x_ = o_ < x_ ? o_ : x_;            \
    atomicMax(&(p2), x_);                                         \
}

// ---------------------------------------------------------------------------
// Prep (1 block): per-cell GT lists (LDS-atomic slots; order nondeterministic
// but all consumers are order-independent) + seed final3 with zero-iou keys.
__global__ void __launch_bounds__(256) k_prep(
    const float4* __restrict__ gt, u32* __restrict__ gtCnt,
    u16* __restrict__ gtIds, u64* __restrict__ final3, int M)
{
    __shared__ u32 l_cnt[NCELL];
    const int tid = threadIdx.x;
    for (int c = tid; c < NCELL; c += 256) l_cnt[c] = 0;
    __syncthreads();

    if (tid < M) {
        float4 g = gt[tid];
        int clx, chx, cly, chy;
        gt_range(g, clx, chx, cly, chy);
        for (int iy = cly; iy <= chy; ++iy)
            for (int ix = clx; ix <= chx; ++ix) {
                int c = iy * NCX + ix;
                u32 slot = atomicAdd(&l_cnt[c], 1u);
                gtIds[(size_t)c * M + slot] = (u16)tid;
            }
        final3[tid * 3 + 0] = 0x00000000FFFFFFFFULL;   // (iou=0, ~0)
        final3[tid * 3 + 1] = 0x00000000FFFFFFFEULL;   // (iou=0, ~1)
        final3[tid * 3 + 2] = 0x00000000FFFFFFFDULL;   // (iou=0, ~2)
    }
    __syncthreads();
    for (int c = tid; c < NCELL; c += 256) gtCnt[c] = l_cnt[c];
}

// ---------------------------------------------------------------------------
// Main (GRID_MAIN blocks, grid-stride): per anchor, walk its cell's GT list;
// compute base assignment (register max) AND insert per-GT top-3 keys into
// the block's LDS table (prefiltered cascade). Epilogue: merge non-zero
// table entries into global final3 (prefiltered cascade).
__global__ void __launch_bounds__(256) k_main(
    const float4* __restrict__ anchor, const float4* __restrict__ gt,
    const u32* __restrict__ gtCnt, const u16* __restrict__ gtIds,
    u64* __restrict__ final3, int* __restrict__ out, int N, int M)
{
    __shared__ float4 s_g[MPAD];
    __shared__ float  s_ga[MPAD];
    __shared__ u64    tbl[3 * MPAD];     // per-block top-3 per GT, 6 KB
    const int tid = threadIdx.x;

    if (tid < M) {
        float4 g = gt[tid];
        s_g[tid]  = g;
        s_ga[tid] = (g.z - g.x) * (g.w - g.y);
    }
    for (int e = tid; e < 3 * MPAD; e += 256) tbl[e] = 0;
    __syncthreads();

    for (int i = blockIdx.x * 256 + tid; i < N; i += 256 * GRID_MAIN) {
        float4 a = anchor[i];
        float area_a = (a.z - a.x) * (a.w - a.y);
        int c   = cell_of(a);
        int cnt = (int)gtCnt[c];
        const u16* list = gtIds + (size_t)c * M;
        u32 nai = ~(u32)i;

        u64 best = 0;
        for (int k = 0; k < cnt; ++k) {
            int m = list[k];
            float4 g = s_g[m];
            float inter, iou;
            IOU_EVAL(a, area_a, g, s_ga[m], inter, iou);
            if (inter > 0.0f) {
                u32 ib = __float_as_uint(iou);
                u64 kb = ((u64)ib << 32) | (~(u32)m);
                best = kb > best ? kb : best;
                u64 kt = ((u64)ib << 32) | nai;
                // racy prefilter safe: tbl[...] only rises; skip only when
                // three >= keys already present
                if (kt > tbl[m * 3 + 2])
                    CASCADE3(tbl[m * 3 + 0], tbl[m * 3 + 1], tbl[m * 3 + 2], kt);
            }
        }
        u32 ib = (u32)(best >> 32);
        int v = -2;
        if (ib < __float_as_uint(NEG_THRESH)) v = -1;   // max iou < 0.3
        if (ib > __float_as_uint(POS_THRESH)) v = (int)(~(u32)best);
        out[i] = v;
    }
    __syncthreads();

    // merge block table -> global final3 (seeds already cover zero-iou fill)
    for (int e = tid; e < 3 * M; e += 256) {
        u64 v = tbl[e];
        if ((u32)(v >> 32) == 0) continue;     // empty / zero-iou: seeded
        int m = e / 3;
        u64* g3 = final3 + m * 3;
        if (v <= g3[2]) continue;              // racy prefilter, safe
        CASCADE3(g3[0], g3[1], g3[2], v);
    }
}

// ---------------------------------------------------------------------------
// Claims: read final top-3 per GT, forced-claim scatter-max via a 1024-slot
// LDS hash table (tag = anchor+1 via atomicCAS, value = 64-bit LDS atomicMax
// of claim key). Winner (unique per anchor) writes out[].
// claim key = (anchor<<32)|(gt+1); max key == last-writer gt == reference.
__global__ void __launch_bounds__(256) k_claims(
    const u64* __restrict__ final3, int* __restrict__ out, int M)
{
    __shared__ u64 s_key[3 * MPAD];
    __shared__ u64 h_val[HSLOTS];
    __shared__ u32 h_tag[HSLOTS];   // anchor+1; 0 = empty
    const int tid = threadIdx.x;

    for (int i = tid; i < HSLOTS; i += 256) { h_val[i] = 0; h_tag[i] = 0; }

    if (tid < M) {
        u64 q0 = final3[tid * 3 + 0];
        u64 q1 = final3[tid * 3 + 1];
        u64 q2 = final3[tid * 3 + 2];

        float v0 = __uint_as_float((u32)(q0 >> 32));
        float v1 = __uint_as_float((u32)(q1 >> 32));
        float v2 = __uint_as_float((u32)(q2 >> 32));
        u32 a0 = ~(u32)q0;
        u32 a1 = ~(u32)q1;
        u32 a2 = ~(u32)q2;

        int npos = (v0 > POS_THRESH) + (v1 > POS_THRESH) + (v2 > POS_THRESH);
        bool low = npos < 3;

        s_key[tid * 3 + 0] = ((u64)a0 << 32) | (u32)(tid + 1);   // k==0 forced
        s_key[tid * 3 + 1] = (low && v1 > CLAIM_THRESH)
            ? (((u64)a1 << 32) | (u32)(tid + 1)) : 0ULL;
        s_key[tid * 3 + 2] = (low && v2 > CLAIM_THRESH)
            ? (((u64)a2 << 32) | (u32)(tid + 1)) : 0ULL;
    }
    __syncthreads();

    const int tote = 3 * M;
    // insert: claim slot by anchor tag, atomicMax the claim key
    for (int e = tid; e < tote; e += 256) {
        u64 my = s_key[e];
        if (my == 0) continue;
        u32 myA = (u32)(my >> 32);
        u32 slot = (myA * 2654435761u) & (HSLOTS - 1);
        while (true) {
            u32 prev = atomicCAS(&h_tag[slot], 0u, myA + 1u);
            if (prev == 0u || prev == myA + 1u) {
                atomicMax(&h_val[slot], my);
                break;
            }
            slot = (slot + 1) & (HSLOTS - 1);
        }
    }
    __syncthreads();
    // resolve: claim wins iff it holds the max key for its anchor
    for (int e = tid; e < tote; e += 256) {
        u64 my = s_key[e];
        if (my == 0) continue;
        u32 myA = (u32)(my >> 32);
        u32 slot = (myA * 2654435761u) & (HSLOTS - 1);
        while (h_tag[slot] != myA + 1u) slot = (slot + 1) & (HSLOTS - 1);
        if (h_val[slot] == my) out[myA] = (int)(my & 0xffffffffULL) - 1;
    }
}

// ---------------------------------------------------------------------------
extern "C" void kernel_launch(void* const* d_in, const int* in_sizes, int n_in,
                              void* d_out, int out_size, void* d_ws, size_t ws_size,
                              hipStream_t stream) {
    const float4* anchor = (const float4*)d_in[0];
    const float4* gt     = (const float4*)d_in[1];
    int N = in_sizes[0] / 4;
    int M = in_sizes[1] / 4;
    int* out = (int*)d_out;

    // workspace layout (<1 MB; ws_size ~= 256 MB)
    char* ws = (char*)d_ws;
    size_t off = 0;
    auto alloc = [&](size_t bytes, size_t align) -> void* {
        off = (off + align - 1) / align * align;
        void* p = ws + off;
        off += bytes;
        return p;
    };
    u32* gtCnt  = (u32*)alloc(NCELL * 4, 64);
    u64* final3 = (u64*)alloc((size_t)MPAD * 3 * 8, 64);
    u16* gtIds  = (u16*)alloc((size_t)NCELL * M * 2, 2);

    k_prep<<<1, 256, 0, stream>>>(gt, gtCnt, gtIds, final3, M);
    k_main<<<GRID_MAIN, 256, 0, stream>>>(anchor, gt, gtCnt, gtIds,
                                          final3, out, N, M);
    k_claims<<<1, 256, 0, stream>>>(final3, out, M);
}

// Round 16
// 111.379 us; speedup vs baseline: 1.1098x; 1.1098x over previous
//
#include <hip/hip_runtime.h>
#include <stdint.h>

// S3FD anchor assignment — single-pass pair enumeration, round 16.
// d_in[0]: anchor [N,4] f32, d_in[1]: gt [M,4] f32. d_out: assign [N] int32.
//
// Round 15 post-mortem: k_main 106 us at VALUBusy 12% — all 1024 co-resident
// blocks finished together and burst ~1M global atomicMax onto final3's 75
// cachelines (round 9's atomic-serialization disease at the merge level).
// Round 16: 16 SHADOW copies of final3, 64B-padded per-(GT,shadow) slot;
// block merges into shadow (blockIdx & 15) -> contention /16, lines x43.
// Shadows zero-init'd by k_prep; zero-iou seeds moved into k_claims'
// accumulator init (zeros can never displace seeds: 0 > (0,~2) is false).
// k_main walk + k_claims hash scatter-max byte-identical to round 15.
//
// Key encoding (exact jax semantics), per-GT top-3:
//   key = (iou_bits << 32) | ~anchor_idx    (stable top_k: higher iou, then
//                                            lower anchor index wins)
// Seeds (0,~0),(0,~1),(0,~2) reproduce the reference's index-ordered zero
// fill (benign-duplication argument proven rounds 8-15).

typedef unsigned int u32;
typedef unsigned short u16;
typedef unsigned long long u64;

#define POS_THRESH 0.5f
#define NEG_THRESH 0.3f
#define CLAIM_THRESH 0.1f

constexpr int NCX = 32, NCY = 32, NCELL = NCX * NCY;  // 32x32 cells, 32 px
constexpr float INV_CELL = 0.03125f;                  // 1/32
constexpr float MARGIN = 64.5f;   // max anchor half-extent (<64.001) + slack
constexpr int MPAD = 256;         // padded GT count (M = 200)
constexpr int HSLOTS = 1024;      // claims hash table slots
constexpr int GRID_MAIN = 1024;   // k_main blocks (~4/CU resident)
constexpr int NSHADOW = 16;       // shadow copies of final3
constexpr int SSTRIDE = 8;        // u64 per (GT,shadow) slot = 64B line

// IoU expression verbatim from the passing rounds (numpy-exact).
#define IOU_EVAL(a, areaA, g, areaG, inter, iou) {                \
    float ltx = fmaxf(a.x, g.x), lty = fmaxf(a.y, g.y);           \
    float rbx = fminf(a.z, g.z), rby = fminf(a.w, g.w);           \
    float ww = fmaxf(rbx - ltx, 0.0f);                            \
    float hh = fmaxf(rby - lty, 0.0f);                            \
    inter = ww * hh;                                              \
    iou = 0.0f;                                                   \
    if (inter > 0.0f) iou = inter / ((areaA + areaG) - inter);    \
}

#define INS3(t0, t1, t2, k) do {                                  \
    if ((k) > (t2)) {                                             \
        if ((k) > (t0))      { t2 = t1; t1 = t0; t0 = (k); }      \
        else if ((k) > (t1)) { t2 = t1; t1 = (k); }               \
        else                 { t2 = (k); }                        \
    } } while (0)

__device__ __forceinline__ int cell_of(const float4 a) {
    float cx = 0.5f * (a.x + a.z);
    float cy = 0.5f * (a.y + a.w);
    int ix = (int)(cx * INV_CELL);
    int iy = (int)(cy * INV_CELL);
    ix = ix < 0 ? 0 : (ix > NCX - 1 ? NCX - 1 : ix);
    iy = iy < 0 ? 0 : (iy > NCY - 1 ? NCY - 1 : iy);
    return iy * NCX + ix;
}

__device__ __forceinline__ void gt_range(const float4 g, int& clx, int& chx,
                                         int& cly, int& chy) {
    clx = (int)floorf((g.x - MARGIN) * INV_CELL);
    chx = (int)floorf((g.z + MARGIN) * INV_CELL);
    cly = (int)floorf((g.y - MARGIN) * INV_CELL);
    chy = (int)floorf((g.w + MARGIN) * INV_CELL);
    clx = clx < 0 ? 0 : (clx > NCX - 1 ? NCX - 1 : clx);
    chx = chx < 0 ? 0 : (chx > NCX - 1 ? NCX - 1 : chx);
    cly = cly < 0 ? 0 : (cly > NCY - 1 ? NCY - 1 : cly);
    chy = chy < 0 ? 0 : (chy > NCY - 1 ? NCY - 1 : chy);
}

// Concurrent sorted top-3 insert: atomicMax cascade (proven round 15).
#define CASCADE3(p0, p1, p2, key) {                               \
    u64 x_ = (key);                                               \
    u64 o_ = atomicMax(&(p0), x_); x_ = o_ < x_ ? o_ : x_;        \
    o_ = atomicMax(&(p1), x_); x_ = o_ < x_ ? o_ : x_;            \
    atomicMax(&(p2), x_);                                         \
}

// ---------------------------------------------------------------------------
// Prep (1 block): per-cell GT lists + zero the shadow tables.
__global__ void __launch_bounds__(256) k_prep(
    const float4* __restrict__ gt, u32* __restrict__ gtCnt,
    u16* __restrict__ gtIds, u64* __restrict__ shadow3, int M)
{
    __shared__ u32 l_cnt[NCELL];
    const int tid = threadIdx.x;
    for (int c = tid; c < NCELL; c += 256) l_cnt[c] = 0;
    __syncthreads();

    // zero only the 3 used u64 per (GT, shadow) slot
    for (int e = tid; e < M * NSHADOW; e += 256) {
        u64* slot = shadow3 + (size_t)e * SSTRIDE;
        slot[0] = 0; slot[1] = 0; slot[2] = 0;
    }

    if (tid < M) {
        float4 g = gt[tid];
        int clx, chx, cly, chy;
        gt_range(g, clx, chx, cly, chy);
        for (int iy = cly; iy <= chy; ++iy)
            for (int ix = clx; ix <= chx; ++ix) {
                int c = iy * NCX + ix;
                u32 slot = atomicAdd(&l_cnt[c], 1u);
                gtIds[(size_t)c * M + slot] = (u16)tid;
            }
    }
    __syncthreads();
    for (int c = tid; c < NCELL; c += 256) gtCnt[c] = l_cnt[c];
}

// ---------------------------------------------------------------------------
// Main (GRID_MAIN blocks, grid-stride): per anchor, walk its cell's GT list;
// base assignment (register max) + per-GT top-3 into block LDS table
// (prefiltered cascade). Epilogue: merge into shadow (blockIdx & 15).
__global__ void __launch_bounds__(256) k_main(
    const float4* __restrict__ anchor, const float4* __restrict__ gt,
    const u32* __restrict__ gtCnt, const u16* __restrict__ gtIds,
    u64* __restrict__ shadow3, int* __restrict__ out, int N, int M)
{
    __shared__ float4 s_g[MPAD];
    __shared__ float  s_ga[MPAD];
    __shared__ u64    tbl[3 * MPAD];     // per-block top-3 per GT, 6 KB
    const int tid = threadIdx.x;

    if (tid < M) {
        float4 g = gt[tid];
        s_g[tid]  = g;
        s_ga[tid] = (g.z - g.x) * (g.w - g.y);
    }
    for (int e = tid; e < 3 * MPAD; e += 256) tbl[e] = 0;
    __syncthreads();

    for (int i = blockIdx.x * 256 + tid; i < N; i += 256 * GRID_MAIN) {
        float4 a = anchor[i];
        float area_a = (a.z - a.x) * (a.w - a.y);
        int c   = cell_of(a);
        int cnt = (int)gtCnt[c];
        const u16* list = gtIds + (size_t)c * M;
        u32 nai = ~(u32)i;

        u64 best = 0;
        for (int k = 0; k < cnt; ++k) {
            int m = list[k];
            float4 g = s_g[m];
            float inter, iou;
            IOU_EVAL(a, area_a, g, s_ga[m], inter, iou);
            if (inter > 0.0f) {
                u32 ib = __float_as_uint(iou);
                u64 kb = ((u64)ib << 32) | (~(u32)m);
                best = kb > best ? kb : best;
                u64 kt = ((u64)ib << 32) | nai;
                if (kt > tbl[m * 3 + 2])   // racy prefilter, safe (monotone)
                    CASCADE3(tbl[m * 3 + 0], tbl[m * 3 + 1], tbl[m * 3 + 2], kt);
            }
        }
        u32 ib = (u32)(best >> 32);
        int v = -2;
        if (ib < __float_as_uint(NEG_THRESH)) v = -1;   // max iou < 0.3
        if (ib > __float_as_uint(POS_THRESH)) v = (int)(~(u32)best);
        out[i] = v;
    }
    __syncthreads();

    // merge block table -> this block's shadow copy
    const int s = blockIdx.x & (NSHADOW - 1);
    for (int e = tid; e < 3 * M; e += 256) {
        u64 v = tbl[e];
        if ((u32)(v >> 32) == 0) continue;     // zero-iou: seeded in claims
        int m = e / 3;
        u64* g3 = shadow3 + ((size_t)m * NSHADOW + s) * SSTRIDE;
        if (v <= g3[2]) continue;              // racy prefilter, safe
        CASCADE3(g3[0], g3[1], g3[2], v);
    }
}

// ---------------------------------------------------------------------------
// Claims: accumulate per-GT top-3 from seeds + 16 shadows, then forced-claim
// scatter-max via the proven 1024-slot LDS hash (tag CAS + 64-bit atomicMax).
// claim key = (anchor<<32)|(gt+1); max key == last-writer gt == reference.
__global__ void __launch_bounds__(256) k_claims(
    const u64* __restrict__ shadow3, int* __restrict__ out, int M)
{
    __shared__ u64 s_key[3 * MPAD];
    __shared__ u64 h_val[HSLOTS];
    __shared__ u32 h_tag[HSLOTS];   // anchor+1; 0 = empty
    const int tid = threadIdx.x;

    for (int i = tid; i < HSLOTS; i += 256) { h_val[i] = 0; h_tag[i] = 0; }

    if (tid < M) {
        // accumulators start at the zero-iou seeds (index-ordered fill)
        u64 q0 = 0x00000000FFFFFFFFULL;   // (iou=0, ~0)
        u64 q1 = 0x00000000FFFFFFFEULL;   // (iou=0, ~1)
        u64 q2 = 0x00000000FFFFFFFDULL;   // (iou=0, ~2)
        const u64* base = shadow3 + (size_t)tid * NSHADOW * SSTRIDE;
        for (int s = 0; s < NSHADOW; ++s) {
            const u64* p = base + (size_t)s * SSTRIDE;
            INS3(q0, q1, q2, p[0]);
            INS3(q0, q1, q2, p[1]);
            INS3(q0, q1, q2, p[2]);
        }

        float v0 = __uint_as_float((u32)(q0 >> 32));
        float v1 = __uint_as_float((u32)(q1 >> 32));
        float v2 = __uint_as_float((u32)(q2 >> 32));
        u32 a0 = ~(u32)q0;
        u32 a1 = ~(u32)q1;
        u32 a2 = ~(u32)q2;

        int npos = (v0 > POS_THRESH) + (v1 > POS_THRESH) + (v2 > POS_THRESH);
        bool low = npos < 3;

        s_key[tid * 3 + 0] = ((u64)a0 << 32) | (u32)(tid + 1);   // k==0 forced
        s_key[tid * 3 + 1] = (low && v1 > CLAIM_THRESH)
            ? (((u64)a1 << 32) | (u32)(tid + 1)) : 0ULL;
        s_key[tid * 3 + 2] = (low && v2 > CLAIM_THRESH)
            ? (((u64)a2 << 32) | (u32)(tid + 1)) : 0ULL;
    }
    __syncthreads();

    const int tote = 3 * M;
    // insert: claim slot by anchor tag, atomicMax the claim key
    for (int e = tid; e < tote; e += 256) {
        u64 my = s_key[e];
        if (my == 0) continue;
        u32 myA = (u32)(my >> 32);
        u32 slot = (myA * 2654435761u) & (HSLOTS - 1);
        while (true) {
            u32 prev = atomicCAS(&h_tag[slot], 0u, myA + 1u);
            if (prev == 0u || prev == myA + 1u) {
                atomicMax(&h_val[slot], my);
                break;
            }
            slot = (slot + 1) & (HSLOTS - 1);
        }
    }
    __syncthreads();
    // resolve: claim wins iff it holds the max key for its anchor
    for (int e = tid; e < tote; e += 256) {
        u64 my = s_key[e];
        if (my == 0) continue;
        u32 myA = (u32)(my >> 32);
        u32 slot = (myA * 2654435761u) & (HSLOTS - 1);
        while (h_tag[slot] != myA + 1u) slot = (slot + 1) & (HSLOTS - 1);
        if (h_val[slot] == my) out[myA] = (int)(my & 0xffffffffULL) - 1;
    }
}

// ---------------------------------------------------------------------------
extern "C" void kernel_launch(void* const* d_in, const int* in_sizes, int n_in,
                              void* d_out, int out_size, void* d_ws, size_t ws_size,
                              hipStream_t stream) {
    const float4* anchor = (const float4*)d_in[0];
    const float4* gt     = (const float4*)d_in[1];
    int N = in_sizes[0] / 4;
    int M = in_sizes[1] / 4;
    int* out = (int*)d_out;

    // workspace layout (<1 MB; ws_size ~= 256 MB)
    char* ws = (char*)d_ws;
    size_t off = 0;
    auto alloc = [&](size_t bytes, size_t align) -> void* {
        off = (off + align - 1) / align * align;
        void* p = ws + off;
        off += bytes;
        return p;
    };
    u32* gtCnt   = (u32*)alloc(NCELL * 4, 64);
    u64* shadow3 = (u64*)alloc((size_t)MPAD * NSHADOW * SSTRIDE * 8, 64);
    u16* gtIds   = (u16*)alloc((size_t)NCELL * M * 2, 2);

    k_prep<<<1, 256, 0, stream>>>(gt, gtCnt, gtIds, shadow3, M);
    k_main<<<GRID_MAIN, 256, 0, stream>>>(anchor, gt, gtCnt, gtIds,
                                          shadow3, out, N, M);
    k_claims<<<1, 256, 0, stream>>>(shadow3, out, M);
}